// Round 4
// baseline (2094.231 us; speedup 1.0000x reference)
//
#include <hip/hip_runtime.h>
#include <cstdint>
#include <cstddef>

// R3: 256 WGs x 1024 threads, 2 rows/WG, k-split 8 (kq=t&7, oq=t>>3).
// Weight slice = 64 f16x2/thread (+~45 working) -> fits 128-VGPR budget ->
// 4 waves/SIMD (16 waves/CU), 2 rows/CU as R1 but 2x wave depth for latency
// hiding. R2 lesson: 128-reg budget with 128 weight regs spills to scratch
// (FETCH_SIZE 578MB); this round weights=64 regs so it must NOT spill.
// Predicted: ~600-750us, VALUBusy 45-55%, Occ 40-50%, FETCH ~20-30MB.

typedef _Float16 f16;
typedef _Float16 f16x2 __attribute__((ext_vector_type(2)));

#define NSTEP 127
#define NSUB 10
#define B_LEN 512
#define S_LEN 128
#define H_LEN 128

__device__ __forceinline__ float dot2acc(f16x2 a, f16x2 b, float c) {
  return __builtin_amdgcn_fdot2(a, b, c, false);
}
__device__ __forceinline__ f16x2 bchalf(unsigned int u) {
  return __builtin_bit_cast(f16x2, u);
}

#define DOT4R(acc, wr, base, dv)                          \
  do {                                                    \
    acc = dot2acc((wr)[(base) + 0], bchalf((dv).x), acc); \
    acc = dot2acc((wr)[(base) + 1], bchalf((dv).y), acc); \
    acc = dot2acc((wr)[(base) + 2], bchalf((dv).z), acc); \
    acc = dot2acc((wr)[(base) + 3], bchalf((dv).w), acc); \
  } while (0)

// JAX threefry2x32 (20 rounds) -- bit-exact (verified: absmax 9.8e-4).
__device__ __forceinline__ void tf2x32(unsigned int k0, unsigned int k1,
                                       unsigned int& x0, unsigned int& x1) {
  unsigned int ks[3] = {k0, k1, k0 ^ k1 ^ 0x1BD11BDAu};
  x0 += ks[0];
  x1 += ks[1];
  const int R[2][4] = {{13, 15, 26, 6}, {17, 29, 16, 24}};
#pragma unroll
  for (int g = 0; g < 5; ++g) {
#pragma unroll
    for (int j = 0; j < 4; ++j) {
      const int r = R[g & 1][j];
      x0 += x1;
      x1 = (x1 << r) | (x1 >> (32 - r));
      x1 ^= x0;
    }
    x0 += ks[(g + 1) % 3];
    x1 += ks[(g + 2) % 3] + (unsigned int)(g + 1);
  }
}

__device__ __forceinline__ float erfinv_f32(float x) {
  float w = -log1pf(-x * x);
  float p;
  if (w < 5.0f) {
    w = w - 2.5f;
    p = 2.81022636e-08f;
    p = fmaf(p, w, 3.43273939e-07f);
    p = fmaf(p, w, -3.5233877e-06f);
    p = fmaf(p, w, -4.39150654e-06f);
    p = fmaf(p, w, 0.00021858087f);
    p = fmaf(p, w, -0.00125372503f);
    p = fmaf(p, w, -0.00417768164f);
    p = fmaf(p, w, 0.246640727f);
    p = fmaf(p, w, 1.50140941f);
  } else {
    w = sqrtf(w) - 3.0f;
    p = -0.000200214257f;
    p = fmaf(p, w, 0.000100950558f);
    p = fmaf(p, w, 0.00134934322f);
    p = fmaf(p, w, -0.00367342844f);
    p = fmaf(p, w, 0.00573950773f);
    p = fmaf(p, w, -0.0076224613f);
    p = fmaf(p, w, 0.00943887047f);
    p = fmaf(p, w, 1.00167406f);
    p = fmaf(p, w, 2.83297682f);
  }
  return p * x;
}

__device__ __forceinline__ float frcp(float x) {
  return __builtin_amdgcn_rcpf(x);
}
__device__ __forceinline__ float fsig(float x) {
  return frcp(1.0f + __expf(-x));
}
__device__ __forceinline__ float ftanh_fast(float x) {
  return 1.0f - 2.0f * frcp(__expf(2.0f * x) + 1.0f);
}
__device__ __forceinline__ float fsoftplus(float x) {
  return fmaxf(x, 0.0f) + __logf(1.0f + __expf(-fabsf(x)));
}

// ---- td precompute: one block per step i; writes wsTd[i]
__global__ __launch_bounds__(256) void td_kernel(
    const float* __restrict__ times, const int* __restrict__ non_zero,
    float* __restrict__ wsTd) {
  __shared__ float sA[256], sB[256];
  __shared__ int sC[256];
  const int i = blockIdx.x;
  const int t = threadIdx.x;
  float s1 = 0.f, s2 = 0.f;
  int c = 0;
  for (int b = t; b < B_LEN; b += 256) {
    const int nz = non_zero[b];
    const float t1 = times[b * S_LEN + i + 1];
    const bool v = (i < nz - 1) && (t1 != 0.0f);
    if (v) {
      c += 1;
      s1 += times[b * S_LEN + i];
      s2 += t1;
    }
  }
  sA[t] = s1;
  sB[t] = s2;
  sC[t] = c;
  __syncthreads();
  for (int o = 128; o > 0; o >>= 1) {
    if (t < o) {
      sA[t] += sA[t + o];
      sB[t] += sB[t + o];
      sC[t] += sC[t + o];
    }
    __syncthreads();
  }
  if (t == 0) {
    const float cnt = (float)((sC[0] < 1) ? 1 : sC[0]);
    const float ts = sA[0] / cnt * 0.02f;
    const float te = sB[0] / cnt * 0.02f;
    wsTd[i] = (te == ts) ? 1.0f : (te - ts);
  }
}

__global__ __launch_bounds__(1024, 4) void sde_fused_kernel(
    const float* __restrict__ inputs, const int* __restrict__ non_zero,
    const float* __restrict__ Wih, const float* __restrict__ Whh,
    const float* __restrict__ bih, const float* __restrict__ bhh,
    const float* __restrict__ dW1, const float* __restrict__ db1,
    const float* __restrict__ dW2, const float* __restrict__ db2,
    const float* __restrict__ gW1, const float* __restrict__ gb1,
    const float* __restrict__ gW2, const float* __restrict__ gb2,
    const float* __restrict__ wsTd, float* __restrict__ out) {
  __shared__ float sZ[NSTEP * NSUB * 2];
  __shared__ float sDt[NSTEP], sSq[NSTEP], sU[NSTEP];
  __shared__ __align__(16) f16 sX[2][H_LEN];
  __shared__ __align__(16) f16 sH2[2][H_LEN];
  __shared__ __align__(16) f16 sH[2][H_LEN];
  __shared__ __align__(16) f16 sAct[2][H_LEN];

  const int t = threadIdx.x;
  const int kq = t & 7;   // k-eighth; reduce via shfl_xor 1,2,4
  const int oq = t >> 3;  // output index 0..127 (oq<64 split is wave-uniform)
  const int kb16 = kq * 16;  // GRU/L1 K-slice base (f16 elements)
  const int kb8 = kq * 8;    // L2 K-slice base
  const int wg = blockIdx.x;
  const int b0 = wg * 2;

  const int La = non_zero[b0] - 1;
  const int Lb = non_zero[b0 + 1] - 1;
  const int Lmax = (La > Lb) ? La : Lb;

  // ---- noise precompute (identical bit-stream to R0/R1)
  for (int idx = t; idx < NSTEP * NSUB * 2; idx += 1024) {
    const int r = idx & 1;
    const int is = idx >> 1;
    unsigned int f0 = 0u, f1 = (unsigned int)is;
    tf2x32(0u, 42u, f0, f1);
    unsigned int y0 = 0u, y1 = (unsigned int)(b0 + r);
    tf2x32(f0, f1, y0, y1);
    const unsigned int bits = y1;
    const float fl = __uint_as_float((bits >> 9) | 0x3F800000u) - 1.0f;
    const float lo = __uint_as_float(0xBF7FFFFFu);
    float u = fl * (1.0f - lo) + lo;
    u = fmaxf(lo, u);
    sZ[idx] = 1.41421356237f * erfinv_f32(u);
  }
  if (t < NSTEP) {
    const float td = wsTd[t];
    sDt[t] = td * 0.1f;
    sSq[t] = sqrtf(td * 0.1f);
    sU[t] = (t == 0) ? 1.0f : __expf(-wsTd[t - 1]);
  }

  // ---- register weight preload (packed f16, k-eighth slices): 64 VGPRs
  f16x2 rWih[3][8], rWhh[3][8];
#pragma unroll
  for (int g = 0; g < 3; ++g) {
    const float* pi = Wih + (size_t)(oq + 128 * g) * 128 + kb16;
    const float* ph = Whh + (size_t)(oq + 128 * g) * 128 + kb16;
#pragma unroll
    for (int c = 0; c < 8; ++c) {
      f16x2 a;
      a[0] = (f16)pi[2 * c];
      a[1] = (f16)pi[2 * c + 1];
      rWih[g][c] = a;
      f16x2 bb;
      bb[0] = (f16)ph[2 * c];
      bb[1] = (f16)ph[2 * c + 1];
      rWhh[g][c] = bb;
    }
  }
  f16x2 rW1[8];
  {
    const float* p1 = (oq < 64) ? (dW1 + (size_t)oq * 128 + kb16)
                                : (gW1 + (size_t)(oq - 64) * 128 + kb16);
#pragma unroll
    for (int c = 0; c < 8; ++c) {
      f16x2 a;
      a[0] = (f16)p1[2 * c];
      a[1] = (f16)p1[2 * c + 1];
      rW1[c] = a;
    }
  }
  f16x2 rW2d[4], rW2g[4];
  {
    const float* pd = dW2 + (size_t)oq * 64 + kb8;
    const float* pg = gW2 + (size_t)oq * 64 + kb8;
#pragma unroll
    for (int c = 0; c < 4; ++c) {
      f16x2 a;
      a[0] = (f16)pd[2 * c];
      a[1] = (f16)pd[2 * c + 1];
      rW2d[c] = a;
      f16x2 bb;
      bb[0] = (f16)pg[2 * c];
      bb[1] = (f16)pg[2 * c + 1];
      rW2g[c] = bb;
    }
  }
  const float bias1 = (oq < 64) ? db1[oq] : gb1[oq - 64];
  const float bias2d = db2[oq], bias2g = gb2[oq];
  const float rB0 = bih[oq] + bhh[oq];
  const float rB1 = bih[oq + 128] + bhh[oq + 128];
  const float rBi2 = bih[oq + 256];
  const float rBh2 = bhh[oq + 256];

  // ---- state (both rows per thread; redundant across kq)
  float h2e[2] = {0.f, 0.f}, h1e[2] = {0.f, 0.f};
  if (kq < 2) sH2[kq][oq] = (f16)0.f;

  const int xr = (t >> 7) & 1;
  const int xe = t & 127;
  const float* xbase = inputs + (size_t)(b0 + xr) * H_LEN + xe;
  const size_t xstride = (size_t)B_LEN * H_LEN;
  float xreg = (t < 256) ? xbase[0] : 0.f;

  __syncthreads();  // sZ, sDt/sSq/sU, sH2 init visible

  for (int i = 0; i < Lmax; ++i) {
    if (t < 256) sX[xr][xe] = (f16)xreg;
    __syncthreads();  // A: sX + sH2 visible
    if (t < 256 && (i + 1) < NSTEP) xreg = xbase[(size_t)(i + 1) * xstride];

    // ---- GRU matvecs: 12 accumulators, 8-dot2 chains each
    float ai0r0 = 0.f, ai1r0 = 0.f, ai2r0 = 0.f;
    float ah0r0 = 0.f, ah1r0 = 0.f, ah2r0 = 0.f;
    float ai0r1 = 0.f, ai1r1 = 0.f, ai2r1 = 0.f;
    float ah0r1 = 0.f, ah1r1 = 0.f, ah2r1 = 0.f;
    {
      const uint4 xv0a = *(const uint4*)&sX[0][kb16];
      const uint4 xv0b = *(const uint4*)&sX[0][kb16 + 8];
      const uint4 xv1a = *(const uint4*)&sX[1][kb16];
      const uint4 xv1b = *(const uint4*)&sX[1][kb16 + 8];
      const uint4 hv0a = *(const uint4*)&sH2[0][kb16];
      const uint4 hv0b = *(const uint4*)&sH2[0][kb16 + 8];
      const uint4 hv1a = *(const uint4*)&sH2[1][kb16];
      const uint4 hv1b = *(const uint4*)&sH2[1][kb16 + 8];
      DOT4R(ai0r0, rWih[0], 0, xv0a);
      DOT4R(ai0r0, rWih[0], 4, xv0b);
      DOT4R(ai1r0, rWih[1], 0, xv0a);
      DOT4R(ai1r0, rWih[1], 4, xv0b);
      DOT4R(ai2r0, rWih[2], 0, xv0a);
      DOT4R(ai2r0, rWih[2], 4, xv0b);
      DOT4R(ah0r0, rWhh[0], 0, hv0a);
      DOT4R(ah0r0, rWhh[0], 4, hv0b);
      DOT4R(ah1r0, rWhh[1], 0, hv0a);
      DOT4R(ah1r0, rWhh[1], 4, hv0b);
      DOT4R(ah2r0, rWhh[2], 0, hv0a);
      DOT4R(ah2r0, rWhh[2], 4, hv0b);
      DOT4R(ai0r1, rWih[0], 0, xv1a);
      DOT4R(ai0r1, rWih[0], 4, xv1b);
      DOT4R(ai1r1, rWih[1], 0, xv1a);
      DOT4R(ai1r1, rWih[1], 4, xv1b);
      DOT4R(ai2r1, rWih[2], 0, xv1a);
      DOT4R(ai2r1, rWih[2], 4, xv1b);
      DOT4R(ah0r1, rWhh[0], 0, hv1a);
      DOT4R(ah0r1, rWhh[0], 4, hv1b);
      DOT4R(ah1r1, rWhh[1], 0, hv1a);
      DOT4R(ah1r1, rWhh[1], 4, hv1b);
      DOT4R(ah2r1, rWhh[2], 0, hv1a);
      DOT4R(ah2r1, rWhh[2], 4, hv1b);
    }
#define QRED3(v)         \
  v += __shfl_xor(v, 1); \
  v += __shfl_xor(v, 2); \
  v += __shfl_xor(v, 4)
    QRED3(ai0r0); QRED3(ai1r0); QRED3(ai2r0);
    QRED3(ah0r0); QRED3(ah1r0); QRED3(ah2r0);
    QRED3(ai0r1); QRED3(ai1r1); QRED3(ai2r1);
    QRED3(ah0r1); QRED3(ah1r1); QRED3(ah2r1);

    float hg[2], hh[2];
    {
      const float rg0 = fsig(ai0r0 + ah0r0 + rB0);
      const float zg0 = fsig(ai1r0 + ah1r0 + rB1);
      const float nn0 = ftanh_fast(ai2r0 + rBi2 + rg0 * (ah2r0 + rBh2));
      hg[0] = (1.0f - zg0) * nn0 + zg0 * h2e[0];
      const float rg1 = fsig(ai0r1 + ah0r1 + rB0);
      const float zg1 = fsig(ai1r1 + ah1r1 + rB1);
      const float nn1 = ftanh_fast(ai2r1 + rBi2 + rg1 * (ah2r1 + rBh2));
      hg[1] = (1.0f - zg1) * nn1 + zg1 * h2e[1];
    }
    hh[0] = hg[0];
    hh[1] = hg[1];
    if (kq < 2) sH[kq][oq] = (f16)hg[kq];
    __syncthreads();  // B

    const float dt = sDt[i];
    const float sq = sSq[i];
    const float* zrow = &sZ[i * NSUB * 2];
    for (int s = 0; s < NSUB; ++s) {
      // L1: a[oq] per row
      float a0 = 0.f, a1 = 0.f;
      {
        const uint4 h0a = *(const uint4*)&sH[0][kb16];
        const uint4 h0b = *(const uint4*)&sH[0][kb16 + 8];
        const uint4 h1a = *(const uint4*)&sH[1][kb16];
        const uint4 h1b = *(const uint4*)&sH[1][kb16 + 8];
        DOT4R(a0, rW1, 0, h0a);
        DOT4R(a0, rW1, 4, h0b);
        DOT4R(a1, rW1, 0, h1a);
        DOT4R(a1, rW1, 4, h1b);
      }
      QRED3(a0);
      QRED3(a1);
      const float av0 = a0 + bias1;
      const float av1 = a1 + bias1;
      const float act0 = (oq < 64) ? ftanh_fast(av0) : fsoftplus(av0);
      const float act1 = (oq < 64) ? ftanh_fast(av1) : fsoftplus(av1);
      if (kq < 2) sAct[kq][oq] = (f16)(kq ? act1 : act0);
      __syncthreads();
      // L2: f,g per row
      float fa0 = 0.f, ga0 = 0.f, fa1 = 0.f, ga1 = 0.f;
      {
        const uint4 tv0 = *(const uint4*)&sAct[0][kb8];
        const uint4 sv0 = *(const uint4*)&sAct[0][64 + kb8];
        const uint4 tv1 = *(const uint4*)&sAct[1][kb8];
        const uint4 sv1 = *(const uint4*)&sAct[1][64 + kb8];
        DOT4R(fa0, rW2d, 0, tv0);
        DOT4R(ga0, rW2g, 0, sv0);
        DOT4R(fa1, rW2d, 0, tv1);
        DOT4R(ga1, rW2g, 0, sv1);
      }
      QRED3(fa0);
      QRED3(ga0);
      QRED3(fa1);
      QRED3(ga1);
      const float z0 = zrow[s * 2 + 0];
      const float z1 = zrow[s * 2 + 1];
      hh[0] += (fa0 + bias2d) * dt + (ga0 + bias2g) * (sq * z0);
      hh[1] += (fa1 + bias2d) * dt + (ga1 + bias2g) * (sq * z1);
      if (kq < 2) sH[kq][oq] = (f16)hh[kq];
      __syncthreads();
    }
#undef QRED3

    // ---- h1/h2 update (gated per row; frozen once row done)
    if (i < La) {
      h2e[0] = (i == 0) ? hg[0] : (sU[i] * hg[0] + (1.0f - sU[i]) * h1e[0]);
      h1e[0] = hh[0];
    }
    if (i < Lb) {
      h2e[1] = (i == 0) ? hg[1] : (sU[i] * hg[1] + (1.0f - sU[i]) * h1e[1]);
      h1e[1] = hh[1];
    }
    if (kq < 2) sH2[kq][oq] = (f16)h2e[kq];
  }

  if (kq < 2) out[(size_t)(b0 + kq) * H_LEN + oq] = h2e[kq];
}

extern "C" void kernel_launch(void* const* d_in, const int* in_sizes, int n_in,
                              void* d_out, int out_size, void* d_ws,
                              size_t ws_size, hipStream_t stream) {
  (void)in_sizes;
  (void)n_in;
  (void)out_size;
  (void)ws_size;
  const float* inputs = (const float*)d_in[0];
  const float* times = (const float*)d_in[1];
  const int* non_zero = (const int*)d_in[2];
  const float* Wih = (const float*)d_in[3];
  const float* Whh = (const float*)d_in[4];
  const float* bih = (const float*)d_in[5];
  const float* bhh = (const float*)d_in[6];
  const float* dW1 = (const float*)d_in[7];
  const float* db1 = (const float*)d_in[8];
  const float* dW2 = (const float*)d_in[9];
  const float* db2 = (const float*)d_in[10];
  const float* gW1 = (const float*)d_in[11];
  const float* gb1 = (const float*)d_in[12];
  const float* gW2 = (const float*)d_in[13];
  const float* gb2 = (const float*)d_in[14];
  float* out = (float*)d_out;
  float* wsTd = (float*)d_ws;

  hipLaunchKernelGGL(td_kernel, dim3(NSTEP), dim3(256), 0, stream, times,
                     non_zero, wsTd);
  hipLaunchKernelGGL(sde_fused_kernel, dim3(B_LEN / 2), dim3(1024), 0, stream,
                     inputs, non_zero, Wih, Whh, bih, bhh, dW1, db1, dW2, db2,
                     gW1, gb1, gW2, gb2, wsTd, out);
}

// Round 5
// 1203.855 us; speedup vs baseline: 1.7396x; 1.7396x over previous
//
#include <hip/hip_runtime.h>
#include <cstdint>
#include <cstddef>

// R4 = R1 (best, 1388us) + DPP quad-perm reductions (no ds_bpermute shfl).
// Theory: R1 is DS-pipe-bound (176 ds_read_b128 + 144 shfl->ds_bpermute per
// thread-step; VALU only 31%). k-split=4 reduce hops are xor1/xor2 ==
// DPP quad_perm -> pure VALU, removes ~144 DS ops + 2x120cy serial latency
// per reduce point. Also merged r/z gate partial sums before reduce (12->8).
// R2/R3 lesson: keep 512 thr, 2 rows/WG, 184 VGPR, 1 WG/CU -- no spill.
// Predicted: ~900-1050us, VALUBusy ~40%, FETCH ~19MB, VGPR ~184.

typedef _Float16 f16;
typedef _Float16 f16x2 __attribute__((ext_vector_type(2)));

#define NSTEP 127
#define NSUB 10
#define B_LEN 512
#define S_LEN 128
#define H_LEN 128

__device__ __forceinline__ float dot2acc(f16x2 a, f16x2 b, float c) {
  return __builtin_amdgcn_fdot2(a, b, c, false);
}
__device__ __forceinline__ f16x2 bchalf(unsigned int u) {
  return __builtin_bit_cast(f16x2, u);
}

// Sum over the 4 lanes of a quad (our kq group) via DPP quad_perm. VALU-only.
__device__ __forceinline__ float qred4(float v) {
  int a = __builtin_bit_cast(int, v);
  int b = __builtin_amdgcn_update_dpp(0, a, 0xB1, 0xF, 0xF, true);  // xor 1
  float v1 = v + __builtin_bit_cast(float, b);
  int c = __builtin_bit_cast(int, v1);
  int d = __builtin_amdgcn_update_dpp(0, c, 0x4E, 0xF, 0xF, true);  // xor 2
  return v1 + __builtin_bit_cast(float, d);
}

#define DOT4R(acc, wr, base, dv)                          \
  do {                                                    \
    acc = dot2acc((wr)[(base) + 0], bchalf((dv).x), acc); \
    acc = dot2acc((wr)[(base) + 1], bchalf((dv).y), acc); \
    acc = dot2acc((wr)[(base) + 2], bchalf((dv).z), acc); \
    acc = dot2acc((wr)[(base) + 3], bchalf((dv).w), acc); \
  } while (0)

// JAX threefry2x32 (20 rounds) -- bit-exact (verified: absmax 9.8e-4).
__device__ __forceinline__ void tf2x32(unsigned int k0, unsigned int k1,
                                       unsigned int& x0, unsigned int& x1) {
  unsigned int ks[3] = {k0, k1, k0 ^ k1 ^ 0x1BD11BDAu};
  x0 += ks[0];
  x1 += ks[1];
  const int R[2][4] = {{13, 15, 26, 6}, {17, 29, 16, 24}};
#pragma unroll
  for (int g = 0; g < 5; ++g) {
#pragma unroll
    for (int j = 0; j < 4; ++j) {
      const int r = R[g & 1][j];
      x0 += x1;
      x1 = (x1 << r) | (x1 >> (32 - r));
      x1 ^= x0;
    }
    x0 += ks[(g + 1) % 3];
    x1 += ks[(g + 2) % 3] + (unsigned int)(g + 1);
  }
}

__device__ __forceinline__ float erfinv_f32(float x) {
  float w = -log1pf(-x * x);
  float p;
  if (w < 5.0f) {
    w = w - 2.5f;
    p = 2.81022636e-08f;
    p = fmaf(p, w, 3.43273939e-07f);
    p = fmaf(p, w, -3.5233877e-06f);
    p = fmaf(p, w, -4.39150654e-06f);
    p = fmaf(p, w, 0.00021858087f);
    p = fmaf(p, w, -0.00125372503f);
    p = fmaf(p, w, -0.00417768164f);
    p = fmaf(p, w, 0.246640727f);
    p = fmaf(p, w, 1.50140941f);
  } else {
    w = sqrtf(w) - 3.0f;
    p = -0.000200214257f;
    p = fmaf(p, w, 0.000100950558f);
    p = fmaf(p, w, 0.00134934322f);
    p = fmaf(p, w, -0.00367342844f);
    p = fmaf(p, w, 0.00573950773f);
    p = fmaf(p, w, -0.0076224613f);
    p = fmaf(p, w, 0.00943887047f);
    p = fmaf(p, w, 1.00167406f);
    p = fmaf(p, w, 2.83297682f);
  }
  return p * x;
}

__device__ __forceinline__ float frcp(float x) {
  return __builtin_amdgcn_rcpf(x);
}
__device__ __forceinline__ float fsig(float x) {
  return frcp(1.0f + __expf(-x));
}
__device__ __forceinline__ float ftanh_fast(float x) {
  return 1.0f - 2.0f * frcp(__expf(2.0f * x) + 1.0f);
}
__device__ __forceinline__ float fsoftplus(float x) {
  return fmaxf(x, 0.0f) + __logf(1.0f + __expf(-fabsf(x)));
}

// ---- td precompute: one block per step i; writes wsTd[i]
__global__ __launch_bounds__(256) void td_kernel(
    const float* __restrict__ times, const int* __restrict__ non_zero,
    float* __restrict__ wsTd) {
  __shared__ float sA[256], sB[256];
  __shared__ int sC[256];
  const int i = blockIdx.x;
  const int t = threadIdx.x;
  float s1 = 0.f, s2 = 0.f;
  int c = 0;
  for (int b = t; b < B_LEN; b += 256) {
    const int nz = non_zero[b];
    const float t1 = times[b * S_LEN + i + 1];
    const bool v = (i < nz - 1) && (t1 != 0.0f);
    if (v) {
      c += 1;
      s1 += times[b * S_LEN + i];
      s2 += t1;
    }
  }
  sA[t] = s1;
  sB[t] = s2;
  sC[t] = c;
  __syncthreads();
  for (int o = 128; o > 0; o >>= 1) {
    if (t < o) {
      sA[t] += sA[t + o];
      sB[t] += sB[t + o];
      sC[t] += sC[t + o];
    }
    __syncthreads();
  }
  if (t == 0) {
    const float cnt = (float)((sC[0] < 1) ? 1 : sC[0]);
    const float ts = sA[0] / cnt * 0.02f;
    const float te = sB[0] / cnt * 0.02f;
    wsTd[i] = (te == ts) ? 1.0f : (te - ts);
  }
}

__global__ __launch_bounds__(512, 2) void sde_fused_kernel(
    const float* __restrict__ inputs, const int* __restrict__ non_zero,
    const float* __restrict__ Wih, const float* __restrict__ Whh,
    const float* __restrict__ bih, const float* __restrict__ bhh,
    const float* __restrict__ dW1, const float* __restrict__ db1,
    const float* __restrict__ dW2, const float* __restrict__ db2,
    const float* __restrict__ gW1, const float* __restrict__ gb1,
    const float* __restrict__ gW2, const float* __restrict__ gb2,
    const float* __restrict__ wsTd, float* __restrict__ out) {
  __shared__ float sZ[NSTEP * NSUB * 2];
  __shared__ float sDt[NSTEP], sSq[NSTEP], sU[NSTEP];
  __shared__ __align__(16) f16 sX[2][H_LEN];
  __shared__ __align__(16) f16 sH2[2][H_LEN];
  __shared__ __align__(16) f16 sH[2][H_LEN];
  __shared__ __align__(16) f16 sAct[2][H_LEN];

  const int t = threadIdx.x;
  const int kq = t & 3;    // k-quarter; reduce via DPP quad_perm
  const int oq = t >> 2;   // output index 0..127
  const int kb32 = kq * 32;
  const int kb16 = kq * 16;
  const int wg = blockIdx.x;
  const int b0 = wg * 2;

  const int La = non_zero[b0] - 1;
  const int Lb = non_zero[b0 + 1] - 1;
  const int Lmax = (La > Lb) ? La : Lb;

  // ---- noise precompute (identical bit-stream to R0/R1)
  for (int idx = t; idx < NSTEP * NSUB * 2; idx += 512) {
    const int r = idx & 1;
    const int is = idx >> 1;
    unsigned int f0 = 0u, f1 = (unsigned int)is;
    tf2x32(0u, 42u, f0, f1);
    unsigned int y0 = 0u, y1 = (unsigned int)(b0 + r);
    tf2x32(f0, f1, y0, y1);
    const unsigned int bits = y1;
    const float fl = __uint_as_float((bits >> 9) | 0x3F800000u) - 1.0f;
    const float lo = __uint_as_float(0xBF7FFFFFu);
    float u = fl * (1.0f - lo) + lo;
    u = fmaxf(lo, u);
    sZ[idx] = 1.41421356237f * erfinv_f32(u);
  }
  if (t < NSTEP) {
    const float td = wsTd[t];
    sDt[t] = td * 0.1f;
    sSq[t] = sqrtf(td * 0.1f);
    sU[t] = (t == 0) ? 1.0f : __expf(-wsTd[t - 1]);
  }

  // ---- register weight preload (packed f16, k-quarter slices)
  f16x2 rWih[3][16], rWhh[3][16];
#pragma unroll
  for (int g = 0; g < 3; ++g) {
    const float* pi = Wih + (size_t)(oq + 128 * g) * 128 + kb32;
    const float* ph = Whh + (size_t)(oq + 128 * g) * 128 + kb32;
#pragma unroll
    for (int c = 0; c < 16; ++c) {
      f16x2 a;
      a[0] = (f16)pi[2 * c];
      a[1] = (f16)pi[2 * c + 1];
      rWih[g][c] = a;
      f16x2 b;
      b[0] = (f16)ph[2 * c];
      b[1] = (f16)ph[2 * c + 1];
      rWhh[g][c] = b;
    }
  }
  f16x2 rW1[16];
  {
    const float* p1 = (oq < 64) ? (dW1 + (size_t)oq * 128 + kb32)
                                : (gW1 + (size_t)(oq - 64) * 128 + kb32);
#pragma unroll
    for (int c = 0; c < 16; ++c) {
      f16x2 a;
      a[0] = (f16)p1[2 * c];
      a[1] = (f16)p1[2 * c + 1];
      rW1[c] = a;
    }
  }
  f16x2 rW2d[8], rW2g[8];
  {
    const float* pd = dW2 + (size_t)oq * 64 + kb16;
    const float* pg = gW2 + (size_t)oq * 64 + kb16;
#pragma unroll
    for (int c = 0; c < 8; ++c) {
      f16x2 a;
      a[0] = (f16)pd[2 * c];
      a[1] = (f16)pd[2 * c + 1];
      rW2d[c] = a;
      f16x2 b;
      b[0] = (f16)pg[2 * c];
      b[1] = (f16)pg[2 * c + 1];
      rW2g[c] = b;
    }
  }
  const float bias1 = (oq < 64) ? db1[oq] : gb1[oq - 64];
  const float bias2d = db2[oq], bias2g = gb2[oq];
  const float rB0 = bih[oq] + bhh[oq];
  const float rB1 = bih[oq + 128] + bhh[oq + 128];
  const float rBi2 = bih[oq + 256];
  const float rBh2 = bhh[oq + 256];

  // ---- state
  float h2e[2] = {0.f, 0.f}, h1e[2] = {0.f, 0.f};
  if (kq < 2) sH2[kq][oq] = (f16)0.f;

  const int xr = (t >> 7) & 1;
  const int xe = t & 127;
  const float* xbase = inputs + (size_t)(b0 + xr) * H_LEN + xe;
  const size_t xstride = (size_t)B_LEN * H_LEN;
  float xreg = (t < 256) ? xbase[0] : 0.f;

  __syncthreads();  // sZ, sDt/sSq/sU, sH2 init visible

  for (int i = 0; i < Lmax; ++i) {
    if (t < 256) sX[xr][xe] = (f16)xreg;
    __syncthreads();  // A: sX + sH2 visible
    if (t < 256 && (i + 1) < NSTEP) xreg = xbase[(size_t)(i + 1) * xstride];

    // ---- GRU matvecs: 12 accumulators, 16-dot2 chains each
    float ai0r0 = 0.f, ai0r1 = 0.f, ai1r0 = 0.f, ai1r1 = 0.f, ai2r0 = 0.f,
          ai2r1 = 0.f;
    float ah0r0 = 0.f, ah0r1 = 0.f, ah1r0 = 0.f, ah1r1 = 0.f, ah2r0 = 0.f,
          ah2r1 = 0.f;
#pragma unroll
    for (int c = 0; c < 4; ++c) {
      const uint4 xv0 = *(const uint4*)&sX[0][kb32 + c * 8];
      const uint4 xv1 = *(const uint4*)&sX[1][kb32 + c * 8];
      const uint4 hv0 = *(const uint4*)&sH2[0][kb32 + c * 8];
      const uint4 hv1 = *(const uint4*)&sH2[1][kb32 + c * 8];
      DOT4R(ai0r0, rWih[0], c * 4, xv0);
      DOT4R(ai0r1, rWih[0], c * 4, xv1);
      DOT4R(ai1r0, rWih[1], c * 4, xv0);
      DOT4R(ai1r1, rWih[1], c * 4, xv1);
      DOT4R(ai2r0, rWih[2], c * 4, xv0);
      DOT4R(ai2r1, rWih[2], c * 4, xv1);
      DOT4R(ah0r0, rWhh[0], c * 4, hv0);
      DOT4R(ah0r1, rWhh[0], c * 4, hv1);
      DOT4R(ah1r0, rWhh[1], c * 4, hv0);
      DOT4R(ah1r1, rWhh[1], c * 4, hv1);
      DOT4R(ah2r0, rWhh[2], c * 4, hv0);
      DOT4R(ah2r1, rWhh[2], c * 4, hv1);
    }
    // r/z gates: sum gi+gh BEFORE reduce (8 reduces instead of 12)
    const float sr0 = qred4(ai0r0 + ah0r0);
    const float sz0 = qred4(ai1r0 + ah1r0);
    const float sr1 = qred4(ai0r1 + ah0r1);
    const float sz1 = qred4(ai1r1 + ah1r1);
    const float in0 = qred4(ai2r0);
    const float in1 = qred4(ai2r1);
    const float hn0 = qred4(ah2r0);
    const float hn1 = qred4(ah2r1);

    float hg[2], hh[2];
    {
      const float rg0 = fsig(sr0 + rB0);
      const float zg0 = fsig(sz0 + rB1);
      const float nn0 = ftanh_fast(in0 + rBi2 + rg0 * (hn0 + rBh2));
      hg[0] = (1.0f - zg0) * nn0 + zg0 * h2e[0];
      const float rg1 = fsig(sr1 + rB0);
      const float zg1 = fsig(sz1 + rB1);
      const float nn1 = ftanh_fast(in1 + rBi2 + rg1 * (hn1 + rBh2));
      hg[1] = (1.0f - zg1) * nn1 + zg1 * h2e[1];
    }
    hh[0] = hg[0];
    hh[1] = hg[1];
    if (kq < 2) sH[kq][oq] = (f16)hg[kq];
    __syncthreads();  // B

    const float dt = sDt[i];
    const float sq = sSq[i];
    const float* zrow = &sZ[i * NSUB * 2];
    for (int s = 0; s < NSUB; ++s) {
      // L1
      float a0 = 0.f, a1 = 0.f;
#pragma unroll
      for (int c = 0; c < 4; ++c) {
        const uint4 hv0 = *(const uint4*)&sH[0][kb32 + c * 8];
        const uint4 hv1 = *(const uint4*)&sH[1][kb32 + c * 8];
        DOT4R(a0, rW1, c * 4, hv0);
        DOT4R(a1, rW1, c * 4, hv1);
      }
      const float av0 = qred4(a0) + bias1;
      const float av1 = qred4(a1) + bias1;
      const float act0 = (oq < 64) ? ftanh_fast(av0) : fsoftplus(av0);
      const float act1 = (oq < 64) ? ftanh_fast(av1) : fsoftplus(av1);
      if (kq < 2) sAct[kq][oq] = (f16)(kq ? act1 : act0);
      __syncthreads();
      // L2
      float fa0 = 0.f, ga0 = 0.f, fa1 = 0.f, ga1 = 0.f;
#pragma unroll
      for (int c = 0; c < 2; ++c) {
        const uint4 tv0 = *(const uint4*)&sAct[0][kb16 + c * 8];
        const uint4 tv1 = *(const uint4*)&sAct[1][kb16 + c * 8];
        const uint4 sv0 = *(const uint4*)&sAct[0][64 + kb16 + c * 8];
        const uint4 sv1 = *(const uint4*)&sAct[1][64 + kb16 + c * 8];
        DOT4R(fa0, rW2d, c * 4, tv0);
        DOT4R(fa1, rW2d, c * 4, tv1);
        DOT4R(ga0, rW2g, c * 4, sv0);
        DOT4R(ga1, rW2g, c * 4, sv1);
      }
      const float f0 = qred4(fa0) + bias2d;
      const float f1 = qred4(fa1) + bias2d;
      const float g0 = qred4(ga0) + bias2g;
      const float g1 = qred4(ga1) + bias2g;
      const float z0 = zrow[s * 2 + 0];
      const float z1 = zrow[s * 2 + 1];
      hh[0] += f0 * dt + g0 * (sq * z0);
      hh[1] += f1 * dt + g1 * (sq * z1);
      if (kq < 2) sH[kq][oq] = (f16)hh[kq];
      __syncthreads();
    }

    // ---- h1/h2 update (gated per row; frozen once row done)
    if (i < La) {
      h2e[0] = (i == 0) ? hg[0] : (sU[i] * hg[0] + (1.0f - sU[i]) * h1e[0]);
      h1e[0] = hh[0];
    }
    if (i < Lb) {
      h2e[1] = (i == 0) ? hg[1] : (sU[i] * hg[1] + (1.0f - sU[i]) * h1e[1]);
      h1e[1] = hh[1];
    }
    if (kq < 2) sH2[kq][oq] = (f16)h2e[kq];
  }

  if (kq < 2) out[(size_t)(b0 + kq) * H_LEN + oq] = h2e[kq];
}

extern "C" void kernel_launch(void* const* d_in, const int* in_sizes, int n_in,
                              void* d_out, int out_size, void* d_ws,
                              size_t ws_size, hipStream_t stream) {
  (void)in_sizes;
  (void)n_in;
  (void)out_size;
  (void)ws_size;
  const float* inputs = (const float*)d_in[0];
  const float* times = (const float*)d_in[1];
  const int* non_zero = (const int*)d_in[2];
  const float* Wih = (const float*)d_in[3];
  const float* Whh = (const float*)d_in[4];
  const float* bih = (const float*)d_in[5];
  const float* bhh = (const float*)d_in[6];
  const float* dW1 = (const float*)d_in[7];
  const float* db1 = (const float*)d_in[8];
  const float* dW2 = (const float*)d_in[9];
  const float* db2 = (const float*)d_in[10];
  const float* gW1 = (const float*)d_in[11];
  const float* gb1 = (const float*)d_in[12];
  const float* gW2 = (const float*)d_in[13];
  const float* gb2 = (const float*)d_in[14];
  float* out = (float*)d_out;
  float* wsTd = (float*)d_ws;

  hipLaunchKernelGGL(td_kernel, dim3(NSTEP), dim3(256), 0, stream, times,
                     non_zero, wsTd);
  hipLaunchKernelGGL(sde_fused_kernel, dim3(B_LEN / 2), dim3(512), 0, stream,
                     inputs, non_zero, Wih, Whh, bih, bhh, dW1, db1, dW2, db2,
                     gW1, gb1, gW2, gb2, wsTd, out);
}

// Round 6
// 955.997 us; speedup vs baseline: 2.1906x; 1.2593x over previous
//
#include <hip/hip_runtime.h>
#include <cstdint>
#include <cstddef>

// R5 = R4 + y-space substep reformulation (halves substep critical path).
// y = [dW1;gW1]h + b1; substep: a=act(y) (elementwise, per-thread);
// y' = y + dt*(A*a_t + c) + sq*z*(B*a_s + e), A=Wc*dW2, B=Wc*gW2 precomputed
// on device (f16). h recovered ONCE per step: h(10) = hg + dt*dW2*Sat
// + 10dt*db2 + sq*gW2*Sas + sq*zsum*gb2, Sat=Σa_t, Sas=Σ z_s*a_s.
// -> 1 barrier + 1 LDS RT + 32 dot2 per substep (was 2+2+64); 13 barriers/step
// (was 22). Raw lgkmcnt-only barrier (no vmcnt drain of x prefetch).
// Straggler-WG chain latency is the binding constraint (occupancy 16.4% ==
// meanL/127 * 25%), so this targets per-substep latency directly.
// Predicted: ~800-880us, FETCH ~19MB (spill tripwire), VGPR ~160-200.

typedef _Float16 f16;
typedef _Float16 f16x2 __attribute__((ext_vector_type(2)));

#define NSTEP 127
#define NSUB 10
#define B_LEN 512
#define S_LEN 128
#define H_LEN 128

__device__ __forceinline__ float dot2acc(f16x2 a, f16x2 b, float c) {
  return __builtin_amdgcn_fdot2(a, b, c, false);
}
__device__ __forceinline__ f16x2 bchalf(unsigned int u) {
  return __builtin_bit_cast(f16x2, u);
}

// Sum over the 4 lanes of a quad (kq group) via DPP quad_perm. VALU-only.
__device__ __forceinline__ float qred4(float v) {
  int a = __builtin_bit_cast(int, v);
  int b = __builtin_amdgcn_update_dpp(0, a, 0xB1, 0xF, 0xF, true);  // xor 1
  float v1 = v + __builtin_bit_cast(float, b);
  int c = __builtin_bit_cast(int, v1);
  int d = __builtin_amdgcn_update_dpp(0, c, 0x4E, 0xF, 0xF, true);  // xor 2
  return v1 + __builtin_bit_cast(float, d);
}

// WG barrier that waits LDS only (no vmcnt drain of in-flight x prefetch).
__device__ __forceinline__ void wg_barrier() {
  asm volatile("s_waitcnt lgkmcnt(0)\n\ts_barrier" ::: "memory");
}

#define DOT4R(acc, wr, base, dv)                          \
  do {                                                    \
    acc = dot2acc((wr)[(base) + 0], bchalf((dv).x), acc); \
    acc = dot2acc((wr)[(base) + 1], bchalf((dv).y), acc); \
    acc = dot2acc((wr)[(base) + 2], bchalf((dv).z), acc); \
    acc = dot2acc((wr)[(base) + 3], bchalf((dv).w), acc); \
  } while (0)

// JAX threefry2x32 (20 rounds) -- bit-exact (verified: absmax 9.8e-4).
__device__ __forceinline__ void tf2x32(unsigned int k0, unsigned int k1,
                                       unsigned int& x0, unsigned int& x1) {
  unsigned int ks[3] = {k0, k1, k0 ^ k1 ^ 0x1BD11BDAu};
  x0 += ks[0];
  x1 += ks[1];
  const int R[2][4] = {{13, 15, 26, 6}, {17, 29, 16, 24}};
#pragma unroll
  for (int g = 0; g < 5; ++g) {
#pragma unroll
    for (int j = 0; j < 4; ++j) {
      const int r = R[g & 1][j];
      x0 += x1;
      x1 = (x1 << r) | (x1 >> (32 - r));
      x1 ^= x0;
    }
    x0 += ks[(g + 1) % 3];
    x1 += ks[(g + 2) % 3] + (unsigned int)(g + 1);
  }
}

__device__ __forceinline__ float erfinv_f32(float x) {
  float w = -log1pf(-x * x);
  float p;
  if (w < 5.0f) {
    w = w - 2.5f;
    p = 2.81022636e-08f;
    p = fmaf(p, w, 3.43273939e-07f);
    p = fmaf(p, w, -3.5233877e-06f);
    p = fmaf(p, w, -4.39150654e-06f);
    p = fmaf(p, w, 0.00021858087f);
    p = fmaf(p, w, -0.00125372503f);
    p = fmaf(p, w, -0.00417768164f);
    p = fmaf(p, w, 0.246640727f);
    p = fmaf(p, w, 1.50140941f);
  } else {
    w = sqrtf(w) - 3.0f;
    p = -0.000200214257f;
    p = fmaf(p, w, 0.000100950558f);
    p = fmaf(p, w, 0.00134934322f);
    p = fmaf(p, w, -0.00367342844f);
    p = fmaf(p, w, 0.00573950773f);
    p = fmaf(p, w, -0.0076224613f);
    p = fmaf(p, w, 0.00943887047f);
    p = fmaf(p, w, 1.00167406f);
    p = fmaf(p, w, 2.83297682f);
  }
  return p * x;
}

__device__ __forceinline__ float frcp(float x) {
  return __builtin_amdgcn_rcpf(x);
}
__device__ __forceinline__ float fsig(float x) {
  return frcp(1.0f + __expf(-x));
}
__device__ __forceinline__ float ftanh_fast(float x) {
  return 1.0f - 2.0f * frcp(__expf(2.0f * x) + 1.0f);
}
__device__ __forceinline__ float fsoftplus(float x) {
  return fmaxf(x, 0.0f) + __logf(1.0f + __expf(-fabsf(x)));
}

// ---- td precompute: one block per step i; writes wsTd[i]
__global__ __launch_bounds__(256) void td_kernel(
    const float* __restrict__ times, const int* __restrict__ non_zero,
    float* __restrict__ wsTd) {
  __shared__ float sA[256], sB[256];
  __shared__ int sC[256];
  const int i = blockIdx.x;
  const int t = threadIdx.x;
  float s1 = 0.f, s2 = 0.f;
  int c = 0;
  for (int b = t; b < B_LEN; b += 256) {
    const int nz = non_zero[b];
    const float t1 = times[b * S_LEN + i + 1];
    const bool v = (i < nz - 1) && (t1 != 0.0f);
    if (v) {
      c += 1;
      s1 += times[b * S_LEN + i];
      s2 += t1;
    }
  }
  sA[t] = s1;
  sB[t] = s2;
  sC[t] = c;
  __syncthreads();
  for (int o = 128; o > 0; o >>= 1) {
    if (t < o) {
      sA[t] += sA[t + o];
      sB[t] += sB[t + o];
      sC[t] += sC[t + o];
    }
    __syncthreads();
  }
  if (t == 0) {
    const float cnt = (float)((sC[0] < 1) ? 1 : sC[0]);
    const float ts = sA[0] / cnt * 0.02f;
    const float te = sB[0] / cnt * 0.02f;
    wsTd[i] = (te == ts) ? 1.0f : (te - ts);
  }
}

// ---- A/B/c/e precompute: A = Wc*dW2 (128x64), B = Wc*gW2, c = Wc*db2,
// e = Wc*gb2, Wc = [dW1; gW1]. One block per output row o.
__global__ __launch_bounds__(128) void ab_kernel(
    const float* __restrict__ dW1, const float* __restrict__ gW1,
    const float* __restrict__ dW2, const float* __restrict__ gW2,
    const float* __restrict__ db2, const float* __restrict__ gb2,
    float* __restrict__ wsC, float* __restrict__ wsE, f16* __restrict__ wsA,
    f16* __restrict__ wsB) {
  __shared__ float sWc[128];
  const int o = blockIdx.x;
  const int j = threadIdx.x;
  sWc[j] = (o < 64) ? dW1[o * 128 + j] : gW1[(o - 64) * 128 + j];
  __syncthreads();
  float acc = 0.f;
  if (j < 64) {
    for (int m = 0; m < 128; ++m) acc += sWc[m] * dW2[m * 64 + j];
    wsA[o * 64 + j] = (f16)acc;
  } else {
    const int jj = j - 64;
    for (int m = 0; m < 128; ++m) acc += sWc[m] * gW2[m * 64 + jj];
    wsB[o * 64 + jj] = (f16)acc;
  }
  if (j == 0) {
    float cc = 0.f;
    for (int m = 0; m < 128; ++m) cc += sWc[m] * db2[m];
    wsC[o] = cc;
  }
  if (j == 1) {
    float ee = 0.f;
    for (int m = 0; m < 128; ++m) ee += sWc[m] * gb2[m];
    wsE[o] = ee;
  }
}

__global__ __launch_bounds__(512, 2) void sde_fused_kernel(
    const float* __restrict__ inputs, const int* __restrict__ non_zero,
    const float* __restrict__ Wih, const float* __restrict__ Whh,
    const float* __restrict__ bih, const float* __restrict__ bhh,
    const float* __restrict__ dW1, const float* __restrict__ db1,
    const float* __restrict__ dW2, const float* __restrict__ db2,
    const float* __restrict__ gW1, const float* __restrict__ gb1,
    const float* __restrict__ gW2, const float* __restrict__ gb2,
    const float* __restrict__ wsTd, const float* __restrict__ wsC,
    const float* __restrict__ wsE, const f16* __restrict__ wsA,
    const f16* __restrict__ wsB, float* __restrict__ out) {
  __shared__ float sZ[NSTEP * NSUB * 2];
  __shared__ float sDt[NSTEP], sSq[NSTEP], sU[NSTEP];
  __shared__ __align__(16) f16 sX[2][H_LEN];
  __shared__ __align__(16) f16 sH2[2][H_LEN];
  __shared__ __align__(16) f16 sH[2][H_LEN];
  __shared__ __align__(16) f16 sActDB[2][2][H_LEN];  // [buf][row][feat]
  __shared__ __align__(16) f16 sSa[2][H_LEN];        // [row][Sat(0:64)|Sas]

  const int t = threadIdx.x;
  const int kq = t & 3;   // k-quarter; reduce via DPP quad_perm
  const int oq = t >> 2;  // output index 0..127 (oq<64 wave-uniform)
  const int kb32 = kq * 32;
  const int kb16 = kq * 16;
  const int wg = blockIdx.x;
  const int b0 = wg * 2;

  const int La = non_zero[b0] - 1;
  const int Lb = non_zero[b0 + 1] - 1;
  const int Lmax = (La > Lb) ? La : Lb;

  // ---- noise precompute (identical bit-stream to R0-R4)
  for (int idx = t; idx < NSTEP * NSUB * 2; idx += 512) {
    const int r = idx & 1;
    const int is = idx >> 1;
    unsigned int f0 = 0u, f1 = (unsigned int)is;
    tf2x32(0u, 42u, f0, f1);
    unsigned int y0 = 0u, y1 = (unsigned int)(b0 + r);
    tf2x32(f0, f1, y0, y1);
    const unsigned int bits = y1;
    const float fl = __uint_as_float((bits >> 9) | 0x3F800000u) - 1.0f;
    const float lo = __uint_as_float(0xBF7FFFFFu);
    float u = fl * (1.0f - lo) + lo;
    u = fmaxf(lo, u);
    sZ[idx] = 1.41421356237f * erfinv_f32(u);
  }
  if (t < NSTEP) {
    const float td = wsTd[t];
    sDt[t] = td * 0.1f;
    sSq[t] = sqrtf(td * 0.1f);
    sU[t] = (t == 0) ? 1.0f : __expf(-wsTd[t - 1]);
  }

  // ---- register weight preload (packed f16): 144 f16x2 total
  f16x2 rWih[3][16], rWhh[3][16];
#pragma unroll
  for (int g = 0; g < 3; ++g) {
    const float* pi = Wih + (size_t)(oq + 128 * g) * 128 + kb32;
    const float* ph = Whh + (size_t)(oq + 128 * g) * 128 + kb32;
#pragma unroll
    for (int c = 0; c < 16; ++c) {
      f16x2 a;
      a[0] = (f16)pi[2 * c];
      a[1] = (f16)pi[2 * c + 1];
      rWih[g][c] = a;
      f16x2 b;
      b[0] = (f16)ph[2 * c];
      b[1] = (f16)ph[2 * c + 1];
      rWhh[g][c] = b;
    }
  }
  f16x2 rW1[16];  // Wc[oq][kb32..+32) for y-init
  {
    const float* p1 = (oq < 64) ? (dW1 + (size_t)oq * 128 + kb32)
                                : (gW1 + (size_t)(oq - 64) * 128 + kb32);
#pragma unroll
    for (int c = 0; c < 16; ++c) {
      f16x2 a;
      a[0] = (f16)p1[2 * c];
      a[1] = (f16)p1[2 * c + 1];
      rW1[c] = a;
    }
  }
  f16x2 wA[8], wB[8];  // A[oq][kq*16..+16), B[oq][...] (f16, precomputed)
  {
    const f16x2* pA = (const f16x2*)wsA + oq * 32 + kq * 8;
    const f16x2* pB = (const f16x2*)wsB + oq * 32 + kq * 8;
#pragma unroll
    for (int c = 0; c < 8; ++c) {
      wA[c] = pA[c];
      wB[c] = pB[c];
    }
  }
  f16x2 rW2d[8], rW2g[8];  // dW2[oq][kb16..), gW2[oq][kb16..) for recovery
  {
    const float* pd = dW2 + (size_t)oq * 64 + kb16;
    const float* pg = gW2 + (size_t)oq * 64 + kb16;
#pragma unroll
    for (int c = 0; c < 8; ++c) {
      f16x2 a;
      a[0] = (f16)pd[2 * c];
      a[1] = (f16)pd[2 * c + 1];
      rW2d[c] = a;
      f16x2 b;
      b[0] = (f16)pg[2 * c];
      b[1] = (f16)pg[2 * c + 1];
      rW2g[c] = b;
    }
  }
  const float bias1 = (oq < 64) ? db1[oq] : gb1[oq - 64];
  const float bias2d = db2[oq], bias2g = gb2[oq];
  const float cB = wsC[oq], eB = wsE[oq];
  const float rB0 = bih[oq] + bhh[oq];
  const float rB1 = bih[oq + 128] + bhh[oq + 128];
  const float rBi2 = bih[oq + 256];
  const float rBh2 = bhh[oq + 256];

  // ---- state
  float h2e[2] = {0.f, 0.f}, h1e[2] = {0.f, 0.f};
  if (kq < 2) sH2[kq][oq] = (f16)0.f;

  const int xr = (t >> 7) & 1;
  const int xe = t & 127;
  const float* xbase = inputs + (size_t)(b0 + xr) * H_LEN + xe;
  const size_t xstride = (size_t)B_LEN * H_LEN;
  float xreg = (t < 256) ? xbase[0] : 0.f;

  __syncthreads();  // sZ, sDt/sSq/sU, sH2 init visible

  for (int i = 0; i < Lmax; ++i) {
    if (t < 256) sX[xr][xe] = (f16)xreg;
    wg_barrier();  // A: sX + sH2 visible
    if (t < 256 && (i + 1) < NSTEP) xreg = xbase[(size_t)(i + 1) * xstride];

    // ---- GRU matvecs: 12 accumulators, 16-dot2 chains each
    float ai0r0 = 0.f, ai0r1 = 0.f, ai1r0 = 0.f, ai1r1 = 0.f, ai2r0 = 0.f,
          ai2r1 = 0.f;
    float ah0r0 = 0.f, ah0r1 = 0.f, ah1r0 = 0.f, ah1r1 = 0.f, ah2r0 = 0.f,
          ah2r1 = 0.f;
#pragma unroll
    for (int c = 0; c < 4; ++c) {
      const uint4 xv0 = *(const uint4*)&sX[0][kb32 + c * 8];
      const uint4 xv1 = *(const uint4*)&sX[1][kb32 + c * 8];
      const uint4 hv0 = *(const uint4*)&sH2[0][kb32 + c * 8];
      const uint4 hv1 = *(const uint4*)&sH2[1][kb32 + c * 8];
      DOT4R(ai0r0, rWih[0], c * 4, xv0);
      DOT4R(ai0r1, rWih[0], c * 4, xv1);
      DOT4R(ai1r0, rWih[1], c * 4, xv0);
      DOT4R(ai1r1, rWih[1], c * 4, xv1);
      DOT4R(ai2r0, rWih[2], c * 4, xv0);
      DOT4R(ai2r1, rWih[2], c * 4, xv1);
      DOT4R(ah0r0, rWhh[0], c * 4, hv0);
      DOT4R(ah0r1, rWhh[0], c * 4, hv1);
      DOT4R(ah1r0, rWhh[1], c * 4, hv0);
      DOT4R(ah1r1, rWhh[1], c * 4, hv1);
      DOT4R(ah2r0, rWhh[2], c * 4, hv0);
      DOT4R(ah2r1, rWhh[2], c * 4, hv1);
    }
    const float sr0 = qred4(ai0r0 + ah0r0);
    const float sz0 = qred4(ai1r0 + ah1r0);
    const float sr1 = qred4(ai0r1 + ah0r1);
    const float sz1 = qred4(ai1r1 + ah1r1);
    const float in0 = qred4(ai2r0);
    const float in1 = qred4(ai2r1);
    const float hn0 = qred4(ah2r0);
    const float hn1 = qred4(ah2r1);

    float hg[2];
    {
      const float rg0 = fsig(sr0 + rB0);
      const float zg0 = fsig(sz0 + rB1);
      const float nn0 = ftanh_fast(in0 + rBi2 + rg0 * (hn0 + rBh2));
      hg[0] = (1.0f - zg0) * nn0 + zg0 * h2e[0];
      const float rg1 = fsig(sr1 + rB0);
      const float zg1 = fsig(sz1 + rB1);
      const float nn1 = ftanh_fast(in1 + rBi2 + rg1 * (hn1 + rBh2));
      hg[1] = (1.0f - zg1) * nn1 + zg1 * h2e[1];
    }
    if (kq < 2) sH[kq][oq] = (f16)hg[kq];
    wg_barrier();  // B: sH (hg) visible

    // ---- y-init: y = Wc*hg + b1 (per thread: its oq, both rows)
    float y0 = 0.f, y1 = 0.f;
#pragma unroll
    for (int c = 0; c < 4; ++c) {
      const uint4 hv0 = *(const uint4*)&sH[0][kb32 + c * 8];
      const uint4 hv1 = *(const uint4*)&sH[1][kb32 + c * 8];
      DOT4R(y0, rW1, c * 4, hv0);
      DOT4R(y1, rW1, c * 4, hv1);
    }
    y0 = qred4(y0) + bias1;
    y1 = qred4(y1) + bias1;

    const float dt = sDt[i];
    const float sq = sSq[i];
    float sacc0 = 0.f, sacc1 = 0.f, zsum0 = 0.f, zsum1 = 0.f;

    // ---- 10 substeps in y-space: 1 barrier + 1 LDS exchange each
    for (int s = 0; s < NSUB; ++s) {
      const float2 zz = *(const float2*)&sZ[(i * NSUB + s) * 2];
      const float a0 = (oq < 64) ? ftanh_fast(y0) : fsoftplus(y0);
      const float a1 = (oq < 64) ? ftanh_fast(y1) : fsoftplus(y1);
      sacc0 += (oq < 64) ? a0 : zz.x * a0;  // Sat | Sas accumulation
      sacc1 += (oq < 64) ? a1 : zz.y * a1;
      zsum0 += zz.x;
      zsum1 += zz.y;
      const int buf = s & 1;
      if (kq < 2) sActDB[buf][kq][oq] = (f16)(kq ? a1 : a0);
      wg_barrier();
      const uint4 t0a = *(const uint4*)&sActDB[buf][0][kb16];
      const uint4 t0b = *(const uint4*)&sActDB[buf][0][kb16 + 8];
      const uint4 s0a = *(const uint4*)&sActDB[buf][0][64 + kb16];
      const uint4 s0b = *(const uint4*)&sActDB[buf][0][64 + kb16 + 8];
      const uint4 t1a = *(const uint4*)&sActDB[buf][1][kb16];
      const uint4 t1b = *(const uint4*)&sActDB[buf][1][kb16 + 8];
      const uint4 s1a = *(const uint4*)&sActDB[buf][1][64 + kb16];
      const uint4 s1b = *(const uint4*)&sActDB[buf][1][64 + kb16 + 8];
      float dA0 = 0.f, dB0 = 0.f, dA1 = 0.f, dB1 = 0.f;
      DOT4R(dA0, wA, 0, t0a);
      DOT4R(dA0, wA, 4, t0b);
      DOT4R(dB0, wB, 0, s0a);
      DOT4R(dB0, wB, 4, s0b);
      DOT4R(dA1, wA, 0, t1a);
      DOT4R(dA1, wA, 4, t1b);
      DOT4R(dB1, wB, 0, s1a);
      DOT4R(dB1, wB, 4, s1b);
      const float redA0 = qred4(dA0);
      const float redB0 = qred4(dB0);
      const float redA1 = qred4(dA1);
      const float redB1 = qred4(dB1);
      y0 += dt * (redA0 + cB) + (sq * zz.x) * (redB0 + eB);
      y1 += dt * (redA1 + cB) + (sq * zz.y) * (redB1 + eB);
    }

    // ---- h recovery: h(10) = hg + dt*dW2*Sat + 10dt*db2 + sq*gW2*Sas
    //                        + sq*zsum*gb2
    if (kq < 2) sSa[kq][oq] = (f16)(kq ? sacc1 : sacc0);
    wg_barrier();
    {
      const uint4 d0a = *(const uint4*)&sSa[0][kb16];
      const uint4 d0b = *(const uint4*)&sSa[0][kb16 + 8];
      const uint4 g0a = *(const uint4*)&sSa[0][64 + kb16];
      const uint4 g0b = *(const uint4*)&sSa[0][64 + kb16 + 8];
      const uint4 d1a = *(const uint4*)&sSa[1][kb16];
      const uint4 d1b = *(const uint4*)&sSa[1][kb16 + 8];
      const uint4 g1a = *(const uint4*)&sSa[1][64 + kb16];
      const uint4 g1b = *(const uint4*)&sSa[1][64 + kb16 + 8];
      float fd0 = 0.f, fg0 = 0.f, fd1 = 0.f, fg1 = 0.f;
      DOT4R(fd0, rW2d, 0, d0a);
      DOT4R(fd0, rW2d, 4, d0b);
      DOT4R(fg0, rW2g, 0, g0a);
      DOT4R(fg0, rW2g, 4, g0b);
      DOT4R(fd1, rW2d, 0, d1a);
      DOT4R(fd1, rW2d, 4, d1b);
      DOT4R(fg1, rW2g, 0, g1a);
      DOT4R(fg1, rW2g, 4, g1b);
      const float redD0 = qred4(fd0);
      const float redG0 = qred4(fg0);
      const float redD1 = qred4(fd1);
      const float redG1 = qred4(fg1);
      const float h1n0 = hg[0] + dt * redD0 + (dt * (float)NSUB) * bias2d +
                         sq * redG0 + (sq * zsum0) * bias2g;
      const float h1n1 = hg[1] + dt * redD1 + (dt * (float)NSUB) * bias2d +
                         sq * redG1 + (sq * zsum1) * bias2g;

      // ---- h1/h2 update (gated per row; frozen once row done)
      if (i < La) {
        h2e[0] = (i == 0) ? hg[0] : (sU[i] * hg[0] + (1.0f - sU[i]) * h1e[0]);
        h1e[0] = h1n0;
      }
      if (i < Lb) {
        h2e[1] = (i == 0) ? hg[1] : (sU[i] * hg[1] + (1.0f - sU[i]) * h1e[1]);
        h1e[1] = h1n1;
      }
    }
    if (kq < 2) sH2[kq][oq] = (f16)h2e[kq];
  }

  if (kq < 2) out[(size_t)(b0 + kq) * H_LEN + oq] = h2e[kq];
}

extern "C" void kernel_launch(void* const* d_in, const int* in_sizes, int n_in,
                              void* d_out, int out_size, void* d_ws,
                              size_t ws_size, hipStream_t stream) {
  (void)in_sizes;
  (void)n_in;
  (void)out_size;
  (void)ws_size;
  const float* inputs = (const float*)d_in[0];
  const float* times = (const float*)d_in[1];
  const int* non_zero = (const int*)d_in[2];
  const float* Wih = (const float*)d_in[3];
  const float* Whh = (const float*)d_in[4];
  const float* bih = (const float*)d_in[5];
  const float* bhh = (const float*)d_in[6];
  const float* dW1 = (const float*)d_in[7];
  const float* db1 = (const float*)d_in[8];
  const float* dW2 = (const float*)d_in[9];
  const float* db2 = (const float*)d_in[10];
  const float* gW1 = (const float*)d_in[11];
  const float* gb1 = (const float*)d_in[12];
  const float* gW2 = (const float*)d_in[13];
  const float* gb2 = (const float*)d_in[14];
  float* out = (float*)d_out;

  char* ws = (char*)d_ws;
  float* wsTd = (float*)ws;                  // [0, 512)
  float* wsC = (float*)(ws + 512);           // [512, 1024)
  float* wsE = (float*)(ws + 1024);          // [1024, 1536)
  f16* wsA = (f16*)(ws + 1536);              // [1536, +16384)
  f16* wsB = (f16*)(ws + 1536 + 16384);      // [17920, +16384)

  hipLaunchKernelGGL(td_kernel, dim3(NSTEP), dim3(256), 0, stream, times,
                     non_zero, wsTd);
  hipLaunchKernelGGL(ab_kernel, dim3(128), dim3(128), 0, stream, dW1, gW1, dW2,
                     gW2, db2, gb2, wsC, wsE, wsA, wsB);
  hipLaunchKernelGGL(sde_fused_kernel, dim3(B_LEN / 2), dim3(512), 0, stream,
                     inputs, non_zero, Wih, Whh, bih, bhh, dW1, db1, dW2, db2,
                     gW1, gb1, gW2, gb2, wsTd, wsC, wsE, wsA, wsB, out);
}